// Round 5
// baseline (304.264 us; speedup 1.0000x reference)
//
#include <hip/hip_runtime.h>
#include <math.h>

#define B_N 2048
#define L_N 64
#define D_N 256   // EMBED_DIM
#define U_N 512   // UNITS
#define NB  8     // batches per attn block (grid = 256 = 1 block/CU)

typedef __attribute__((ext_vector_type(8))) short bf16x8;   // 8 bf16 = 4 VGPRs
typedef __attribute__((ext_vector_type(4))) float f32x4;    // MFMA 16x16 acc

// tanh(x) = 1 - 2/(2^(x*2*log2e)+1)
__device__ __forceinline__ float fast_tanh(float x) {
    float e = __builtin_amdgcn_exp2f(x * 2.8853900817779268f);
    float r = __builtin_amdgcn_rcpf(e + 1.0f);
    return fmaf(-2.0f, r, 1.0f);
}
// fp32 -> bf16 round-to-nearest-even
__device__ __forceinline__ ushort f2bf(float x) {
    uint b = __float_as_uint(x);
    uint r = (b + 0x7FFF + ((b >> 16) & 1)) >> 16;
    return (ushort)r;
}
__device__ __forceinline__ float bf2f(ushort u) {
    uint v = ((uint)u) << 16;
    return __uint_as_float(v);
}

// ---------------------------------------------------------------------------
// K0: pack W1 [256,512] and W2 [512,512] fp32 -> bf16 MFMA B-fragment order.
// chunk g = (ntg*KS + ks)*64 + lane holds W[ks*32 + (lane>>4)*8 + j][ntg*16 + (lane&15)]
// ---------------------------------------------------------------------------
__global__ __launch_bounds__(256) void pack_weights(
    const float* __restrict__ W1, const float* __restrict__ W2,
    ushort* __restrict__ W1p, ushort* __restrict__ W2p)
{
    ushort tmp[8];
    if (blockIdx.x < 64) {
        int g = blockIdx.x * 256 + threadIdx.x;      // 0..16383
        int ntg = g >> 9, ks = (g >> 6) & 7, lane = g & 63;
        int n  = ntg * 16 + (lane & 15);
        int kb = ks * 32 + (lane >> 4) * 8;
#pragma unroll
        for (int j = 0; j < 8; ++j) tmp[j] = f2bf(W1[(kb + j) * U_N + n]);
        *(uint4*)&W1p[(size_t)g * 8] = *(uint4*)tmp;
    } else {
        int g = (blockIdx.x - 64) * 256 + threadIdx.x;  // 0..32767
        int ntg = g >> 10, ks = (g >> 6) & 15, lane = g & 63;
        int n  = ntg * 16 + (lane & 15);
        int kb = ks * 32 + (lane >> 4) * 8;
#pragma unroll
        for (int j = 0; j < 8; ++j) tmp[j] = f2bf(W2[(kb + j) * U_N + n]);
        *(uint4*)&W2p[(size_t)g * 8] = *(uint4*)tmp;
    }
}

// ---------------------------------------------------------------------------
// K1: ph = hidden @ W2 + b1 + b2 via bf16 MFMA, stored bf16. (R0 version)
// ---------------------------------------------------------------------------
__global__ __launch_bounds__(256) void proj_h_mfma(
    const float* __restrict__ hidden, const ushort* __restrict__ W2p,
    const float* __restrict__ b1, const float* __restrict__ b2,
    ushort* __restrict__ ph)
{
    __shared__ ushort As[16 * 512];   // 16 KB

    const int t  = threadIdx.x;
    const int b0 = blockIdx.x * 16;
    const int u0 = blockIdx.y * 128;

#pragma unroll
    for (int i = 0; i < 4; ++i) {
        int f = t + i * 256;
        int m = f >> 6, c = f & 63;
        float4 x0 = *(const float4*)&hidden[(b0 + m) * U_N + c * 8];
        float4 x1 = *(const float4*)&hidden[(b0 + m) * U_N + c * 8 + 4];
        ushort tmp[8] = {f2bf(x0.x), f2bf(x0.y), f2bf(x0.z), f2bf(x0.w),
                         f2bf(x1.x), f2bf(x1.y), f2bf(x1.z), f2bf(x1.w)};
        *(uint4*)&As[(m * 64 + (c ^ (m & 7))) * 8] = *(uint4*)tmp;
    }
    __syncthreads();

    const int w = t >> 6, lane = t & 63;
    const int ml = lane & 15, q = lane >> 4;

    f32x4 acc[2];
#pragma unroll
    for (int nt = 0; nt < 2; ++nt) acc[nt] = (f32x4){0.f, 0.f, 0.f, 0.f};

    for (int ks = 0; ks < 16; ++ks) {
        int c = ks * 4 + q;
        bf16x8 a = *(const bf16x8*)&As[(ml * 64 + (c ^ (ml & 7))) * 8];
        bf16x8 bb[2];
#pragma unroll
        for (int nt = 0; nt < 2; ++nt) {
            int ntg = blockIdx.y * 8 + w * 2 + nt;
            bb[nt] = *(const bf16x8*)&W2p[(size_t)((ntg * 16 + ks) * 64 + lane) * 8];
        }
#pragma unroll
        for (int nt = 0; nt < 2; ++nt)
            acc[nt] = __builtin_amdgcn_mfma_f32_16x16x32_bf16(a, bb[nt], acc[nt], 0, 0, 0);
    }

#pragma unroll
    for (int nt = 0; nt < 2; ++nt) {
        int n = u0 + (w * 2 + nt) * 16 + ml;
        float bias = b1[n] + b2[n];
#pragma unroll
        for (int r = 0; r < 4; ++r)
            ph[(size_t)(b0 + q * 4 + r) * U_N + n] = f2bf(acc[nt][r] + bias);
    }
}

// ---------------------------------------------------------------------------
// K2: fused attention, 512 threads = 8 waves, wave owns a 64-u strip.
// Identical pipeline to R4 (issue-early/write-late halves, acc[4][4] held
// once, A-frags read once). ONE-VARIABLE FIX vs R4: force the 1-block/CU
// allocation target. Evidence R3 vs R4: the allocator caps VGPR at the
// LDS-implied max occupancy (R4: 70 KB -> 2 blocks/CU fit -> 4 waves/SIMD
// -> 128-VGPR cap -> 26 MB scratch spill). Fix: __launch_bounds__(512,2)
// (2 waves/EU = 1 block/CU for an 8-wave block) AND pad As past 80 KB so a
// 2nd block cannot co-reside -> cap 256, demand ~150 fits, no spill.
// ---------------------------------------------------------------------------
__global__ __launch_bounds__(512, 2) void attn_kernel(
    const float* __restrict__ features, const ushort* __restrict__ W1p,
    const float* __restrict__ V, const float* __restrict__ bV,
    const ushort* __restrict__ ph, float* __restrict__ out)
{
    // 2 x (32 KB live + 12 KB pad) = 88 KB: pad forces 1 block/CU (see above).
    __shared__ ushort As[2][64 * 256 + 6144];
    __shared__ float lpart[8][64];
    __shared__ float ctxp[2][256];
    __shared__ float wls[64];

    const int t    = threadIdx.x;        // 0..511
    const int w    = t >> 6;             // 0..7
    const int lane = t & 63;
    const int ml   = lane & 15;
    const int q    = lane >> 4;
    const int b0   = blockIdx.x * NB;

    float4 pa0, pa1, pb0, pb1;           // staging payload: 16 VGPRs, named

    // chunk ch = t + i*512 (i in 0..3); LDS pos (m*32+cc) holds logical chunk
    // (m, cc^(m&31)) so the swizzled a-frag read returns logical (m,c).
#define ISSUE_HALF(bb, i0) do {                                               \
        const float* fb_ = features + (size_t)(bb) * (L_N * D_N);             \
        { int ch_ = t + (i0) * 512; int m_ = ch_ >> 5, cc_ = ch_ & 31;        \
          const float* s_ = &fb_[m_ * D_N + (cc_ ^ (m_ & 31)) * 8];           \
          pa0 = *(const float4*)s_; pa1 = *(const float4*)(s_ + 4); }         \
        { int ch_ = t + (i0 + 1) * 512; int m_ = ch_ >> 5, cc_ = ch_ & 31;    \
          const float* s_ = &fb_[m_ * D_N + (cc_ ^ (m_ & 31)) * 8];           \
          pb0 = *(const float4*)s_; pb1 = *(const float4*)(s_ + 4); }         \
    } while (0)

#define WRITE_HALF(buf, i0) do {                                              \
        { int ch_ = t + (i0) * 512; int m_ = ch_ >> 5, cc_ = ch_ & 31;        \
          ushort tv_[8] = {f2bf(pa0.x), f2bf(pa0.y), f2bf(pa0.z), f2bf(pa0.w),\
                           f2bf(pa1.x), f2bf(pa1.y), f2bf(pa1.z), f2bf(pa1.w)};\
          *(uint4*)&As[buf][((m_ * 32 + cc_)) * 8] = *(uint4*)tv_; }          \
        { int ch_ = t + (i0 + 1) * 512; int m_ = ch_ >> 5, cc_ = ch_ & 31;    \
          ushort tv_[8] = {f2bf(pb0.x), f2bf(pb0.y), f2bf(pb0.z), f2bf(pb0.w),\
                           f2bf(pb1.x), f2bf(pb1.y), f2bf(pb1.z), f2bf(pb1.w)};\
          *(uint4*)&As[buf][((m_ * 32 + cc_)) * 8] = *(uint4*)tv_; }          \
    } while (0)

#define KSTEP(ks) do {                                                        \
        if ((ks) < 7) {                                                       \
            _Pragma("unroll")                                                 \
            for (int nt = 0; nt < 4; ++nt)                                    \
                bfn[nt] = *(const bf16x8*)&W1w[(size_t)((nt * 8 + (ks) + 1) * 64 + lane) * 8]; \
        }                                                                     \
        bf16x8 a_[4];                                                         \
        _Pragma("unroll")                                                     \
        for (int mt = 0; mt < 4; ++mt) {                                      \
            int m_ = mt * 16 + ml, c_ = (ks) * 4 + q;                         \
            a_[mt] = *(const bf16x8*)&As[cur][(m_ * 32 + (c_ ^ (m_ & 31))) * 8]; \
        }                                                                     \
        _Pragma("unroll")                                                     \
        for (int nt = 0; nt < 4; ++nt)                                        \
            _Pragma("unroll")                                                 \
            for (int mt = 0; mt < 4; ++mt)                                    \
                acc[mt][nt] = __builtin_amdgcn_mfma_f32_16x16x32_bf16(        \
                    a_[mt], bfc[nt], acc[mt][nt], 0, 0, 0);                   \
        if ((ks) < 7) {                                                       \
            _Pragma("unroll")                                                 \
            for (int nt = 0; nt < 4; ++nt) bfc[nt] = bfn[nt];                 \
        }                                                                     \
    } while (0)

    // prologue: stage b0 into buffer 0 (both halves)
    ISSUE_HALF(b0, 0);
    WRITE_HALF(0, 0);
    ISSUE_HALF(b0, 2);
    WRITE_HALF(0, 2);
    __syncthreads();

    const ushort* W1w = W1p + (size_t)(w * 4) * 8 * 64 * 8;  // wave's 64-u strip (4 ntg)
    int cur = 0;

    for (int bi = 0; bi < NB; ++bi) {
        const int b = b0 + bi;
        const bool pre = (bi + 1 < NB);

        // T14 issue-early: first half of b+1's tile, drains under ks 0..3
        if (pre) ISSUE_HALF(b + 1, 0);
        __builtin_amdgcn_sched_barrier(0);

        f32x4 acc[4][4];
#pragma unroll
        for (int mt = 0; mt < 4; ++mt)
#pragma unroll
            for (int nt = 0; nt < 4; ++nt)
                acc[mt][nt] = (f32x4){0.f, 0.f, 0.f, 0.f};

        bf16x8 bfc[4], bfn[4];
#pragma unroll
        for (int nt = 0; nt < 4; ++nt)
            bfc[nt] = *(const bf16x8*)&W1w[(size_t)((nt * 8) * 64 + lane) * 8];

        KSTEP(0); KSTEP(1); KSTEP(2); KSTEP(3);

        // write-late half 0 (loads landed under ks 0..3); issue half 1
        if (pre) {
            WRITE_HALF(cur ^ 1, 0);
            ISSUE_HALF(b + 1, 2);
        }
        __builtin_amdgcn_sched_barrier(0);

        KSTEP(4); KSTEP(5); KSTEP(6); KSTEP(7);

        // fold into persistent lp. D layout: n = nt*16+ml (col), m = mt*16+q*4+r
        float lp[16];
#pragma unroll
        for (int j = 0; j < 16; ++j) lp[j] = 0.f;
#pragma unroll
        for (int nt = 0; nt < 4; ++nt) {
            int n = w * 64 + nt * 16 + ml;
            float phv = bf2f(ph[(size_t)b * U_N + n]);
            float vv  = V[n];
#pragma unroll
            for (int mt = 0; mt < 4; ++mt)
#pragma unroll
                for (int r = 0; r < 4; ++r) {
                    float s = fast_tanh(acc[mt][nt][r] + phv);
                    lp[mt * 4 + r] = fmaf(s, vv, lp[mt * 4 + r]);
                }
        }

        // reduce over the 16 n-lanes (xor 1,2,4,8 stays within q-group)
#pragma unroll
        for (int off = 1; off <= 8; off <<= 1)
#pragma unroll
            for (int j = 0; j < 16; ++j)
                lp[j] += __shfl_xor(lp[j], off);

        // write-late half 1 (loads landed under ks 4..7 + fold)
        if (pre) WRITE_HALF(cur ^ 1, 2);

        if (ml == 0) {
#pragma unroll
            for (int mt = 0; mt < 4; ++mt)
#pragma unroll
                for (int r = 0; r < 4; ++r)
                    lpart[w][mt * 16 + q * 4 + r] = lp[mt * 4 + r];
        }
        __syncthreads();   // BARRIER B: lpart ready (also covers WRITE_H0/H1)

        if (t < 64) {
            float lsum = bV[0];
#pragma unroll
            for (int ww = 0; ww < 8; ++ww) lsum += lpart[ww][t];
            float mx = lsum;
#pragma unroll
            for (int off = 32; off > 0; off >>= 1)
                mx = fmaxf(mx, __shfl_xor(mx, off));
            float e = __expf(lsum - mx);
            float ssum = e;
#pragma unroll
            for (int off = 32; off > 0; off >>= 1)
                ssum += __shfl_xor(ssum, off);
            float wt = e / ssum;
            wls[t] = wt;
            out[(size_t)B_N * D_N + (size_t)b * L_N + t] = wt;
        }
        __syncthreads();   // BARRIER C: wls ready

        // context partials: thread t -> d = t&255, l-half h = t>>8
        {
            int d = t & 255, h = t >> 8;
            float cx = 0.f;
#pragma unroll 8
            for (int li = 0; li < 32; ++li) {
                int l = h * 32 + li;
                ushort u = As[cur][(l * 32 + ((d >> 3) ^ (l & 31))) * 8 + (d & 7)];
                cx = fmaf(wls[l], bf2f(u), cx);
            }
            ctxp[h][d] = cx;
        }
        __syncthreads();   // BARRIER D: ctxp ready; As[cur] free; As[cur^1] staged

        if (t < 256) out[(size_t)b * D_N + t] = ctxp[0][t] + ctxp[1][t];

        cur ^= 1;
    }
#undef ISSUE_HALF
#undef WRITE_HALF
#undef KSTEP
}

// ---------------------------------------------------------------------------
extern "C" void kernel_launch(void* const* d_in, const int* in_sizes, int n_in,
                              void* d_out, int out_size, void* d_ws, size_t ws_size,
                              hipStream_t stream) {
    const float* features = (const float*)d_in[0];
    const float* hidden   = (const float*)d_in[1];
    const float* W1       = (const float*)d_in[2];
    const float* b1       = (const float*)d_in[3];
    const float* W2       = (const float*)d_in[4];
    const float* b2       = (const float*)d_in[5];
    const float* V        = (const float*)d_in[6];
    const float* bV       = (const float*)d_in[7];
    float* out = (float*)d_out;

    // ws: ph bf16 2 MB | W1p 256 KB | W2p 512 KB
    ushort* ph  = (ushort*)d_ws;
    ushort* W1p = (ushort*)((char*)d_ws + (size_t)B_N * U_N * 2);
    ushort* W2p = (ushort*)((char*)d_ws + (size_t)B_N * U_N * 2 + (size_t)D_N * U_N * 2);

    pack_weights<<<192, 256, 0, stream>>>(W1, W2, W1p, W2p);
    proj_h_mfma<<<dim3(B_N / 16, U_N / 128), 256, 0, stream>>>(hidden, W2p, b1, b2, ph);
    attn_kernel<<<B_N / NB, 512, 0, stream>>>(features, W1p, V, bV, ph, out);
}

// Round 6
// 295.545 us; speedup vs baseline: 1.0295x; 1.0295x over previous
//
#include <hip/hip_runtime.h>
#include <math.h>

#define B_N 2048
#define L_N 64
#define D_N 256   // EMBED_DIM
#define U_N 512   // UNITS
#define NB  8     // batches per attn block (grid = 256 = 1 block/CU)

typedef __attribute__((ext_vector_type(8))) short bf16x8;   // 8 bf16 = 4 VGPRs
typedef __attribute__((ext_vector_type(4))) float f32x4;    // MFMA 16x16 acc

// tanh(x) = 1 - 2/(2^(x*2*log2e)+1)
__device__ __forceinline__ float fast_tanh(float x) {
    float e = __builtin_amdgcn_exp2f(x * 2.8853900817779268f);
    float r = __builtin_amdgcn_rcpf(e + 1.0f);
    return fmaf(-2.0f, r, 1.0f);
}
// fp32 -> bf16 round-to-nearest-even
__device__ __forceinline__ ushort f2bf(float x) {
    uint b = __float_as_uint(x);
    uint r = (b + 0x7FFF + ((b >> 16) & 1)) >> 16;
    return (ushort)r;
}
__device__ __forceinline__ float bf2f(ushort u) {
    uint v = ((uint)u) << 16;
    return __uint_as_float(v);
}

// ---------------------------------------------------------------------------
// K0: pack W1 [256,512] and W2 [512,512] fp32 -> bf16 MFMA B-fragment order.
// chunk g = (ntg*KS + ks)*64 + lane holds W[ks*32 + (lane>>4)*8 + j][ntg*16 + (lane&15)]
// ---------------------------------------------------------------------------
__global__ __launch_bounds__(256) void pack_weights(
    const float* __restrict__ W1, const float* __restrict__ W2,
    ushort* __restrict__ W1p, ushort* __restrict__ W2p)
{
    ushort tmp[8];
    if (blockIdx.x < 64) {
        int g = blockIdx.x * 256 + threadIdx.x;      // 0..16383
        int ntg = g >> 9, ks = (g >> 6) & 7, lane = g & 63;
        int n  = ntg * 16 + (lane & 15);
        int kb = ks * 32 + (lane >> 4) * 8;
#pragma unroll
        for (int j = 0; j < 8; ++j) tmp[j] = f2bf(W1[(kb + j) * U_N + n]);
        *(uint4*)&W1p[(size_t)g * 8] = *(uint4*)tmp;
    } else {
        int g = (blockIdx.x - 64) * 256 + threadIdx.x;  // 0..32767
        int ntg = g >> 10, ks = (g >> 6) & 15, lane = g & 63;
        int n  = ntg * 16 + (lane & 15);
        int kb = ks * 32 + (lane >> 4) * 8;
#pragma unroll
        for (int j = 0; j < 8; ++j) tmp[j] = f2bf(W2[(kb + j) * U_N + n]);
        *(uint4*)&W2p[(size_t)g * 8] = *(uint4*)tmp;
    }
}

// ---------------------------------------------------------------------------
// K1: ph = hidden @ W2 + b1 + b2 via bf16 MFMA, stored bf16. (R0 version)
// ---------------------------------------------------------------------------
__global__ __launch_bounds__(256) void proj_h_mfma(
    const float* __restrict__ hidden, const ushort* __restrict__ W2p,
    const float* __restrict__ b1, const float* __restrict__ b2,
    ushort* __restrict__ ph)
{
    __shared__ ushort As[16 * 512];   // 16 KB

    const int t  = threadIdx.x;
    const int b0 = blockIdx.x * 16;
    const int u0 = blockIdx.y * 128;

#pragma unroll
    for (int i = 0; i < 4; ++i) {
        int f = t + i * 256;
        int m = f >> 6, c = f & 63;
        float4 x0 = *(const float4*)&hidden[(b0 + m) * U_N + c * 8];
        float4 x1 = *(const float4*)&hidden[(b0 + m) * U_N + c * 8 + 4];
        ushort tmp[8] = {f2bf(x0.x), f2bf(x0.y), f2bf(x0.z), f2bf(x0.w),
                         f2bf(x1.x), f2bf(x1.y), f2bf(x1.z), f2bf(x1.w)};
        *(uint4*)&As[(m * 64 + (c ^ (m & 7))) * 8] = *(uint4*)tmp;
    }
    __syncthreads();

    const int w = t >> 6, lane = t & 63;
    const int ml = lane & 15, q = lane >> 4;

    f32x4 acc[2];
#pragma unroll
    for (int nt = 0; nt < 2; ++nt) acc[nt] = (f32x4){0.f, 0.f, 0.f, 0.f};

    for (int ks = 0; ks < 16; ++ks) {
        int c = ks * 4 + q;
        bf16x8 a = *(const bf16x8*)&As[(ml * 64 + (c ^ (ml & 7))) * 8];
        bf16x8 bb[2];
#pragma unroll
        for (int nt = 0; nt < 2; ++nt) {
            int ntg = blockIdx.y * 8 + w * 2 + nt;
            bb[nt] = *(const bf16x8*)&W2p[(size_t)((ntg * 16 + ks) * 64 + lane) * 8];
        }
#pragma unroll
        for (int nt = 0; nt < 2; ++nt)
            acc[nt] = __builtin_amdgcn_mfma_f32_16x16x32_bf16(a, bb[nt], acc[nt], 0, 0, 0);
    }

#pragma unroll
    for (int nt = 0; nt < 2; ++nt) {
        int n = u0 + (w * 2 + nt) * 16 + ml;
        float bias = b1[n] + b2[n];
#pragma unroll
        for (int r = 0; r < 4; ++r)
            ph[(size_t)(b0 + q * 4 + r) * U_N + n] = f2bf(acc[nt][r] + bias);
    }
}

// ---------------------------------------------------------------------------
// K2: fused attention, 512 threads = 8 waves, wave owns a 64-u strip.
// R4/R5 pipeline with register demand CUT TO FIT <=128 VGPR (R2/R5 falsified
// "hints raise the cap": allocator never exceeds 128 when hinted; only
// natural sub-128 demand avoids spill). Sheds vs R5:
//   - no bfn[] double-buffer (bb[4] loaded per KSTEP; scheduler has ~15
//     spare regs under the cap to pipeline on its own)          (-16)
//   - A-frag loaded per-mt (single av, dies after its 4 MFMAs)  (-12)
//   - staging payload quartered: pa0,pa1 only (8 regs), 4 issue/write
//     points per iter, 2 KSTEPs (~600-1000 cyc) per HBM drain    (-8)
// Peak ~ acc 64 + bb 16 + av 8 + pa 8 + addr ~20 = ~116 < 128.
// NO launch-bounds min, NO waves_per_eu, NO LDS pad (natural allocation).
// ---------------------------------------------------------------------------
__global__ __launch_bounds__(512) void attn_kernel(
    const float* __restrict__ features, const ushort* __restrict__ W1p,
    const float* __restrict__ V, const float* __restrict__ bV,
    const ushort* __restrict__ ph, float* __restrict__ out)
{
    __shared__ ushort As[2][64 * 256];   // 2 x 32 KB, chunk (m,c) at m*32 + (c^(m&31))
    __shared__ float lpart[8][64];
    __shared__ float ctxp[2][256];
    __shared__ float wls[64];

    const int t    = threadIdx.x;        // 0..511
    const int w    = t >> 6;             // 0..7
    const int lane = t & 63;
    const int ml   = lane & 15;
    const int q    = lane >> 4;
    const int b0   = blockIdx.x * NB;

    float4 pa0, pa1;                     // loop staging payload: 8 VGPRs
    float4 pb0, pb1;                     // prologue-only pair (dead in loop)

    // full tile = 2048 chunks of 8 elems; thread covers chunks t + iq*512.
    // LDS pos (m*32+cc) holds logical chunk (m, cc^(m&31)) so the swizzled
    // a-frag read returns logical (m,c).
#define ISSUE_Q(bb_, iq) do {                                                 \
        const float* fb_ = features + (size_t)(bb_) * (L_N * D_N);            \
        int ch_ = t + (iq) * 512; int m_ = ch_ >> 5, cc_ = ch_ & 31;          \
        const float* s_ = &fb_[m_ * D_N + (cc_ ^ (m_ & 31)) * 8];             \
        pa0 = *(const float4*)s_; pa1 = *(const float4*)(s_ + 4);             \
    } while (0)

#define WRITE_Q(buf, iq) do {                                                 \
        int ch_ = t + (iq) * 512; int m_ = ch_ >> 5, cc_ = ch_ & 31;          \
        ushort tv_[8] = {f2bf(pa0.x), f2bf(pa0.y), f2bf(pa0.z), f2bf(pa0.w),  \
                         f2bf(pa1.x), f2bf(pa1.y), f2bf(pa1.z), f2bf(pa1.w)}; \
        *(uint4*)&As[buf][(m_ * 32 + cc_) * 8] = *(uint4*)tv_;                \
    } while (0)

#define ISSUE_QB(bb_, iq) do {                                                \
        const float* fb_ = features + (size_t)(bb_) * (L_N * D_N);            \
        int ch_ = t + (iq) * 512; int m_ = ch_ >> 5, cc_ = ch_ & 31;          \
        const float* s_ = &fb_[m_ * D_N + (cc_ ^ (m_ & 31)) * 8];             \
        pb0 = *(const float4*)s_; pb1 = *(const float4*)(s_ + 4);             \
    } while (0)

#define WRITE_QB(buf, iq) do {                                                \
        int ch_ = t + (iq) * 512; int m_ = ch_ >> 5, cc_ = ch_ & 31;          \
        ushort tv_[8] = {f2bf(pb0.x), f2bf(pb0.y), f2bf(pb0.z), f2bf(pb0.w),  \
                         f2bf(pb1.x), f2bf(pb1.y), f2bf(pb1.z), f2bf(pb1.w)}; \
        *(uint4*)&As[buf][(m_ * 32 + cc_) * 8] = *(uint4*)tv_;                \
    } while (0)

    // one KSTEP: 4 global B-frag loads (L2-resident W1p), then per-mt
    // {1 ds_read_b128 a-frag -> 4 MFMA}. No explicit prefetch arrays.
#define KSTEP(ks) do {                                                        \
        bf16x8 bb[4];                                                         \
        _Pragma("unroll")                                                     \
        for (int nt = 0; nt < 4; ++nt)                                        \
            bb[nt] = *(const bf16x8*)&W1w[(size_t)((nt * 8 + (ks)) * 64 + lane) * 8]; \
        _Pragma("unroll")                                                     \
        for (int mt = 0; mt < 4; ++mt) {                                      \
            int m_ = mt * 16 + ml, c_ = (ks) * 4 + q;                         \
            bf16x8 av = *(const bf16x8*)&As[cur][(m_ * 32 + (c_ ^ (m_ & 31))) * 8]; \
            _Pragma("unroll")                                                 \
            for (int nt = 0; nt < 4; ++nt)                                    \
                acc[mt][nt] = __builtin_amdgcn_mfma_f32_16x16x32_bf16(        \
                    av, bb[nt], acc[mt][nt], 0, 0, 0);                        \
        }                                                                     \
    } while (0)

    // prologue: stage b0 into buffer 0, quarters paired (2 HBM round trips)
    ISSUE_Q(b0, 0); ISSUE_QB(b0, 1);
    WRITE_Q(0, 0);  WRITE_QB(0, 1);
    ISSUE_Q(b0, 2); ISSUE_QB(b0, 3);
    WRITE_Q(0, 2);  WRITE_QB(0, 3);
    __syncthreads();

    const ushort* W1w = W1p + (size_t)(w * 4) * 8 * 64 * 8;  // wave's 64-u strip (4 ntg)
    int cur = 0;

    for (int bi = 0; bi < NB; ++bi) {
        const int b = b0 + bi;
        const bool pre = (bi + 1 < NB);

        f32x4 acc[4][4];
#pragma unroll
        for (int mt = 0; mt < 4; ++mt)
#pragma unroll
            for (int nt = 0; nt < 4; ++nt)
                acc[mt][nt] = (f32x4){0.f, 0.f, 0.f, 0.f};

        // T14 issue-early / write-late, quarter-granular
        if (pre) ISSUE_Q(b + 1, 0);
        __builtin_amdgcn_sched_barrier(0);
        KSTEP(0); KSTEP(1);
        if (pre) { WRITE_Q(cur ^ 1, 0); ISSUE_Q(b + 1, 1); }
        __builtin_amdgcn_sched_barrier(0);
        KSTEP(2); KSTEP(3);
        if (pre) { WRITE_Q(cur ^ 1, 1); ISSUE_Q(b + 1, 2); }
        __builtin_amdgcn_sched_barrier(0);
        KSTEP(4); KSTEP(5);
        if (pre) { WRITE_Q(cur ^ 1, 2); ISSUE_Q(b + 1, 3); }
        __builtin_amdgcn_sched_barrier(0);
        KSTEP(6); KSTEP(7);
        if (pre) WRITE_Q(cur ^ 1, 3);

        // fold into lp. D layout: n = nt*16+ml (col), m = mt*16+q*4+r
        float lp[16];
#pragma unroll
        for (int j = 0; j < 16; ++j) lp[j] = 0.f;
#pragma unroll
        for (int nt = 0; nt < 4; ++nt) {
            int n = w * 64 + nt * 16 + ml;
            float phv = bf2f(ph[(size_t)b * U_N + n]);
            float vv  = V[n];
#pragma unroll
            for (int mt = 0; mt < 4; ++mt)
#pragma unroll
                for (int r = 0; r < 4; ++r) {
                    float s = fast_tanh(acc[mt][nt][r] + phv);
                    lp[mt * 4 + r] = fmaf(s, vv, lp[mt * 4 + r]);
                }
        }

        // reduce over the 16 n-lanes (xor 1,2,4,8 stays within q-group)
#pragma unroll
        for (int off = 1; off <= 8; off <<= 1)
#pragma unroll
            for (int j = 0; j < 16; ++j)
                lp[j] += __shfl_xor(lp[j], off);

        if (ml == 0) {
#pragma unroll
            for (int mt = 0; mt < 4; ++mt)
#pragma unroll
                for (int r = 0; r < 4; ++r)
                    lpart[w][mt * 16 + q * 4 + r] = lp[mt * 4 + r];
        }
        __syncthreads();   // BARRIER B: lpart ready (covers WRITE_Q 0..3)

        if (t < 64) {
            float lsum = bV[0];
#pragma unroll
            for (int ww = 0; ww < 8; ++ww) lsum += lpart[ww][t];
            float mx = lsum;
#pragma unroll
            for (int off = 32; off > 0; off >>= 1)
                mx = fmaxf(mx, __shfl_xor(mx, off));
            float e = __expf(lsum - mx);
            float ssum = e;
#pragma unroll
            for (int off = 32; off > 0; off >>= 1)
                ssum += __shfl_xor(ssum, off);
            float wt = e / ssum;
            wls[t] = wt;
            out[(size_t)B_N * D_N + (size_t)b * L_N + t] = wt;
        }
        __syncthreads();   // BARRIER C: wls ready

        // context partials: thread t -> d = t&255, l-half h = t>>8
        {
            int d = t & 255, h = t >> 8;
            float cx = 0.f;
#pragma unroll 8
            for (int li = 0; li < 32; ++li) {
                int l = h * 32 + li;
                ushort u = As[cur][(l * 32 + ((d >> 3) ^ (l & 31))) * 8 + (d & 7)];
                cx = fmaf(wls[l], bf2f(u), cx);
            }
            ctxp[h][d] = cx;
        }
        __syncthreads();   // BARRIER D: ctxp ready; As[cur] free; As[cur^1] staged

        if (t < 256) out[(size_t)b * D_N + t] = ctxp[0][t] + ctxp[1][t];

        cur ^= 1;
    }
#undef ISSUE_Q
#undef WRITE_Q
#undef ISSUE_QB
#undef WRITE_QB
#undef KSTEP
}

// ---------------------------------------------------------------------------
extern "C" void kernel_launch(void* const* d_in, const int* in_sizes, int n_in,
                              void* d_out, int out_size, void* d_ws, size_t ws_size,
                              hipStream_t stream) {
    const float* features = (const float*)d_in[0];
    const float* hidden   = (const float*)d_in[1];
    const float* W1       = (const float*)d_in[2];
    const float* b1       = (const float*)d_in[3];
    const float* W2       = (const float*)d_in[4];
    const float* b2       = (const float*)d_in[5];
    const float* V        = (const float*)d_in[6];
    const float* bV       = (const float*)d_in[7];
    float* out = (float*)d_out;

    // ws: ph bf16 2 MB | W1p 256 KB | W2p 512 KB
    ushort* ph  = (ushort*)d_ws;
    ushort* W1p = (ushort*)((char*)d_ws + (size_t)B_N * U_N * 2);
    ushort* W2p = (ushort*)((char*)d_ws + (size_t)B_N * U_N * 2 + (size_t)D_N * U_N * 2);

    pack_weights<<<192, 256, 0, stream>>>(W1, W2, W1p, W2p);
    proj_h_mfma<<<dim3(B_N / 16, U_N / 128), 256, 0, stream>>>(hidden, W2p, b1, b2, ph);
    attn_kernel<<<B_N / NB, 512, 0, stream>>>(features, W1p, V, bV, ph, out);
}

// Round 7
// 281.414 us; speedup vs baseline: 1.0812x; 1.0502x over previous
//
#include <hip/hip_runtime.h>
#include <math.h>

#define B_N 2048
#define L_N 64
#define D_N 256   // EMBED_DIM
#define U_N 512   // UNITS
#define NB  8     // batches per attn block (grid = 256 = 1 block/CU)

typedef __attribute__((ext_vector_type(8))) short bf16x8;   // 8 bf16 = 4 VGPRs
typedef __attribute__((ext_vector_type(4))) float f32x4;    // MFMA 16x16 acc

// tanh(x) = 1 - 2/(2^(x*2*log2e)+1)
__device__ __forceinline__ float fast_tanh(float x) {
    float e = __builtin_amdgcn_exp2f(x * 2.8853900817779268f);
    float r = __builtin_amdgcn_rcpf(e + 1.0f);
    return fmaf(-2.0f, r, 1.0f);
}
// fp32 -> bf16 round-to-nearest-even
__device__ __forceinline__ ushort f2bf(float x) {
    uint b = __float_as_uint(x);
    uint r = (b + 0x7FFF + ((b >> 16) & 1)) >> 16;
    return (ushort)r;
}
__device__ __forceinline__ float bf2f(ushort u) {
    uint v = ((uint)u) << 16;
    return __uint_as_float(v);
}

// async global->LDS 16B: zero VGPR payload, counted in vmcnt.
// global src is PER-LANE; LDS dest is wave-uniform base (HW adds lane*16).
__device__ __forceinline__ void gll16(const ushort* g, ushort* l) {
    __builtin_amdgcn_global_load_lds(
        (const __attribute__((address_space(1))) unsigned int*)g,
        (__attribute__((address_space(3))) unsigned int*)l,
        16, 0, 0);
}

// ---------------------------------------------------------------------------
// K0: pack W1 [256,512] and W2 [512,512] fp32 -> bf16 MFMA B-fragment order.
// chunk g = (ntg*KS + ks)*64 + lane holds W[ks*32 + (lane>>4)*8 + j][ntg*16 + (lane&15)]
// ---------------------------------------------------------------------------
__global__ __launch_bounds__(256) void pack_weights(
    const float* __restrict__ W1, const float* __restrict__ W2,
    ushort* __restrict__ W1p, ushort* __restrict__ W2p)
{
    ushort tmp[8];
    if (blockIdx.x < 64) {
        int g = blockIdx.x * 256 + threadIdx.x;      // 0..16383
        int ntg = g >> 9, ks = (g >> 6) & 7, lane = g & 63;
        int n  = ntg * 16 + (lane & 15);
        int kb = ks * 32 + (lane >> 4) * 8;
#pragma unroll
        for (int j = 0; j < 8; ++j) tmp[j] = f2bf(W1[(kb + j) * U_N + n]);
        *(uint4*)&W1p[(size_t)g * 8] = *(uint4*)tmp;
    } else {
        int g = (blockIdx.x - 64) * 256 + threadIdx.x;  // 0..32767
        int ntg = g >> 10, ks = (g >> 6) & 15, lane = g & 63;
        int n  = ntg * 16 + (lane & 15);
        int kb = ks * 32 + (lane >> 4) * 8;
#pragma unroll
        for (int j = 0; j < 8; ++j) tmp[j] = f2bf(W2[(kb + j) * U_N + n]);
        *(uint4*)&W2p[(size_t)g * 8] = *(uint4*)tmp;
    }
}

// ---------------------------------------------------------------------------
// K1: ph = hidden @ W2 + b1 + b2 via bf16 MFMA, stored bf16. (R0 version)
// ---------------------------------------------------------------------------
__global__ __launch_bounds__(256) void proj_h_mfma(
    const float* __restrict__ hidden, const ushort* __restrict__ W2p,
    const float* __restrict__ b1, const float* __restrict__ b2,
    ushort* __restrict__ ph)
{
    __shared__ ushort As[16 * 512];   // 16 KB

    const int t  = threadIdx.x;
    const int b0 = blockIdx.x * 16;
    const int u0 = blockIdx.y * 128;

#pragma unroll
    for (int i = 0; i < 4; ++i) {
        int f = t + i * 256;
        int m = f >> 6, c = f & 63;
        float4 x0 = *(const float4*)&hidden[(b0 + m) * U_N + c * 8];
        float4 x1 = *(const float4*)&hidden[(b0 + m) * U_N + c * 8 + 4];
        ushort tmp[8] = {f2bf(x0.x), f2bf(x0.y), f2bf(x0.z), f2bf(x0.w),
                         f2bf(x1.x), f2bf(x1.y), f2bf(x1.z), f2bf(x1.w)};
        *(uint4*)&As[(m * 64 + (c ^ (m & 7))) * 8] = *(uint4*)tmp;
    }
    __syncthreads();

    const int w = t >> 6, lane = t & 63;
    const int ml = lane & 15, q = lane >> 4;

    f32x4 acc[2];
#pragma unroll
    for (int nt = 0; nt < 2; ++nt) acc[nt] = (f32x4){0.f, 0.f, 0.f, 0.f};

    for (int ks = 0; ks < 16; ++ks) {
        int c = ks * 4 + q;
        bf16x8 a = *(const bf16x8*)&As[(ml * 64 + (c ^ (ml & 7))) * 8];
        bf16x8 bb[2];
#pragma unroll
        for (int nt = 0; nt < 2; ++nt) {
            int ntg = blockIdx.y * 8 + w * 2 + nt;
            bb[nt] = *(const bf16x8*)&W2p[(size_t)((ntg * 16 + ks) * 64 + lane) * 8];
        }
#pragma unroll
        for (int nt = 0; nt < 2; ++nt)
            acc[nt] = __builtin_amdgcn_mfma_f32_16x16x32_bf16(a, bb[nt], acc[nt], 0, 0, 0);
    }

#pragma unroll
    for (int nt = 0; nt < 2; ++nt) {
        int n = u0 + (w * 2 + nt) * 16 + ml;
        float bias = b1[n] + b2[n];
#pragma unroll
        for (int r = 0; r < 4; ++r)
            ph[(size_t)(b0 + q * 4 + r) * U_N + n] = f2bf(acc[nt][r] + bias);
    }
}

// ---------------------------------------------------------------------------
// K2: fused attention, 512 threads = 8 waves, wave owns a 64-u strip.
// ZERO-REGISTER cross-b staging (fixes the R1/R4/R5/R6 VGPR-128 spill, the
// R3 conversion-pass cost, and keeps R4's A-frags-read-once LDS cut):
//   - features(b+1) fp32 DMA'd via global_load_lds into LDS scratch S
//     (64 KB, linear) during b's compute -- no payload VGPRs at all.
//   - iteration tail: per-wave vmcnt(0) (each wave DMA'd its own 8KB of S,
//     reads only its own region -> no extra barrier), then LDS->LDS convert
//     S -> As[cur^1] bf16 with the a-frag swizzle (16 LDS instr/wave).
//   - KSTEP/fold/softmax/ctx identical to R6 (proven correct).
// Demand ~ acc 64 + bb 16 + av 4 + addr ~20 = ~105 < 128 cliff (6-round
// evidence: 512-thr blocks never get >128; fits => no spill).
// LDS 132 KB -> 1 block/CU. No occupancy hints (R2/R5: hints are ignored).
// ---------------------------------------------------------------------------
__global__ __launch_bounds__(512) void attn_kernel(
    const float* __restrict__ features, const ushort* __restrict__ W1p,
    const float* __restrict__ V, const float* __restrict__ bV,
    const ushort* __restrict__ ph, float* __restrict__ out)
{
    __shared__ float  S[L_N * D_N];      // 64 KB fp32 DMA scratch, linear
    __shared__ ushort As[2][64 * 256];   // 2 x 32 KB bf16, chunk (m,c) at m*32+(c^(m&31))
    __shared__ float lpart[8][64];
    __shared__ float ctxp[2][256];
    __shared__ float wls[64];

    const int t    = threadIdx.x;        // 0..511
    const int w    = t >> 6;             // 0..7
    const int lane = t & 63;
    const int ml   = lane & 15;
    const int q    = lane >> 4;
    const int b0   = blockIdx.x * NB;

    // wave w DMAs its own 8 KB region of S: rows w*8 .. w*8+7 (fp32, linear).
#define ISSUE_DMA(bb_) do {                                                   \
        const float* fsrc_ = features + (size_t)(bb_) * (L_N * D_N) + w * 2048; \
        _Pragma("unroll")                                                     \
        for (int i_ = 0; i_ < 8; ++i_)                                        \
            gll16((const ushort*)(fsrc_ + i_ * 256 + lane * 4),               \
                  (ushort*)&S[w * 2048 + i_ * 256]);                          \
    } while (0)

    // wave w converts its own region: lane reads 16B fp32 (contiguous across
    // the wave), writes 8B bf16 at the swizzled chunk position.
    // fi covers chunk ch = w*256+i*32+(lane>>1), half lane&1; m=w*8+i, c=lane>>1.
#define CONVERT(buf) do {                                                     \
        _Pragma("unroll")                                                     \
        for (int i_ = 0; i_ < 8; ++i_) {                                      \
            float4 x_ = *(const float4*)&S[w * 2048 + i_ * 256 + lane * 4];   \
            ushort tv_[4] = {f2bf(x_.x), f2bf(x_.y), f2bf(x_.z), f2bf(x_.w)}; \
            int m_ = w * 8 + i_, c_ = lane >> 1;                              \
            *(uint2*)&As[buf][(m_ * 32 + (c_ ^ (m_ & 31))) * 8 + (lane & 1) * 4] \
                = *(uint2*)tv_;                                               \
        }                                                                     \
    } while (0)

    // one KSTEP: 4 global B-frag loads (L2-resident W1p), then per-mt
    // {1 ds_read_b128 a-frag -> 4 MFMA}.
#define KSTEP(ks) do {                                                        \
        bf16x8 bb[4];                                                         \
        _Pragma("unroll")                                                     \
        for (int nt = 0; nt < 4; ++nt)                                        \
            bb[nt] = *(const bf16x8*)&W1w[(size_t)((nt * 8 + (ks)) * 64 + lane) * 8]; \
        _Pragma("unroll")                                                     \
        for (int mt = 0; mt < 4; ++mt) {                                      \
            int m_ = mt * 16 + ml, c_ = (ks) * 4 + q;                         \
            bf16x8 av = *(const bf16x8*)&As[cur][(m_ * 32 + (c_ ^ (m_ & 31))) * 8]; \
            _Pragma("unroll")                                                 \
            for (int nt = 0; nt < 4; ++nt)                                    \
                acc[mt][nt] = __builtin_amdgcn_mfma_f32_16x16x32_bf16(        \
                    av, bb[nt], acc[mt][nt], 0, 0, 0);                        \
        }                                                                     \
    } while (0)

    // V / bV preload (loop-invariant, 5 regs)
    float vv4[4];
#pragma unroll
    for (int nt = 0; nt < 4; ++nt) vv4[nt] = V[w * 64 + nt * 16 + ml];
    const float bV0 = bV[0];

    // prologue: DMA b0 -> S, convert into As[0]
    ISSUE_DMA(b0);
    asm volatile("s_waitcnt vmcnt(0)" ::: "memory");
    CONVERT(0);
    __syncthreads();

    const ushort* W1w = W1p + (size_t)(w * 4) * 8 * 64 * 8;  // wave's 64-u strip (4 ntg)
    int cur = 0;

    for (int bi = 0; bi < NB; ++bi) {
        const int b = b0 + bi;
        const bool pre = (bi + 1 < NB);

        // zero-reg async staging of b+1 -> S; drains under this iteration
        if (pre) ISSUE_DMA(b + 1);
        __builtin_amdgcn_sched_barrier(0);

        // ph values for this b (4 u16 loads, consumed after KSTEPs)
        ushort phu[4];
#pragma unroll
        for (int nt = 0; nt < 4; ++nt)
            phu[nt] = ph[(size_t)b * U_N + w * 64 + nt * 16 + ml];

        f32x4 acc[4][4];
#pragma unroll
        for (int mt = 0; mt < 4; ++mt)
#pragma unroll
            for (int nt = 0; nt < 4; ++nt)
                acc[mt][nt] = (f32x4){0.f, 0.f, 0.f, 0.f};

        KSTEP(0); KSTEP(1); KSTEP(2); KSTEP(3);
        KSTEP(4); KSTEP(5); KSTEP(6); KSTEP(7);

        // fold into lp. D layout: n = nt*16+ml (col), m = mt*16+q*4+r
        float lp[16];
#pragma unroll
        for (int j = 0; j < 16; ++j) lp[j] = 0.f;
#pragma unroll
        for (int nt = 0; nt < 4; ++nt) {
            float phv = bf2f(phu[nt]);
            float vv  = vv4[nt];
#pragma unroll
            for (int mt = 0; mt < 4; ++mt)
#pragma unroll
                for (int r = 0; r < 4; ++r) {
                    float s = fast_tanh(acc[mt][nt][r] + phv);
                    lp[mt * 4 + r] = fmaf(s, vv, lp[mt * 4 + r]);
                }
        }

        // reduce over the 16 n-lanes (xor 1,2,4,8 stays within q-group)
#pragma unroll
        for (int off = 1; off <= 8; off <<= 1)
#pragma unroll
            for (int j = 0; j < 16; ++j)
                lp[j] += __shfl_xor(lp[j], off);

        if (ml == 0) {
#pragma unroll
            for (int mt = 0; mt < 4; ++mt)
#pragma unroll
                for (int r = 0; r < 4; ++r)
                    lpart[w][mt * 16 + q * 4 + r] = lp[mt * 4 + r];
        }
        __syncthreads();   // BARRIER B: lpart ready

        if (t < 64) {
            float lsum = bV0;
#pragma unroll
            for (int ww = 0; ww < 8; ++ww) lsum += lpart[ww][t];
            float mx = lsum;
#pragma unroll
            for (int off = 32; off > 0; off >>= 1)
                mx = fmaxf(mx, __shfl_xor(mx, off));
            float e = __expf(lsum - mx);
            float ssum = e;
#pragma unroll
            for (int off = 32; off > 0; off >>= 1)
                ssum += __shfl_xor(ssum, off);
            float wt = e / ssum;
            wls[t] = wt;
            out[(size_t)B_N * D_N + (size_t)b * L_N + t] = wt;
        }
        __syncthreads();   // BARRIER C: wls ready

        // context partials: thread t -> d = t&255, l-half h = t>>8
        {
            int d = t & 255, h = t >> 8;
            float cx = 0.f;
#pragma unroll 8
            for (int li = 0; li < 32; ++li) {
                int l = h * 32 + li;
                ushort u = As[cur][(l * 32 + ((d >> 3) ^ (l & 31))) * 8 + (d & 7)];
                cx = fmaf(wls[l], bf2f(u), cx);
            }
            ctxp[h][d] = cx;
        }
        __syncthreads();   // BARRIER D: ctxp ready; all As[cur] reads done

        if (t < 256) out[(size_t)b * D_N + t] = ctxp[0][t] + ctxp[1][t];

        // iteration tail: own-wave DMA drained, convert own region S->As[cur^1]
        if (pre) {
            asm volatile("s_waitcnt vmcnt(0)" ::: "memory");
            CONVERT(cur ^ 1);
        }
        __syncthreads();   // BARRIER E: As[cur^1] visible to all waves
        cur ^= 1;
    }
#undef ISSUE_DMA
#undef CONVERT
#undef KSTEP
}

// ---------------------------------------------------------------------------
extern "C" void kernel_launch(void* const* d_in, const int* in_sizes, int n_in,
                              void* d_out, int out_size, void* d_ws, size_t ws_size,
                              hipStream_t stream) {
    const float* features = (const float*)d_in[0];
    const float* hidden   = (const float*)d_in[1];
    const float* W1       = (const float*)d_in[2];
    const float* b1       = (const float*)d_in[3];
    const float* W2       = (const float*)d_in[4];
    const float* b2       = (const float*)d_in[5];
    const float* V        = (const float*)d_in[6];
    const float* bV       = (const float*)d_in[7];
    float* out = (float*)d_out;

    // ws: ph bf16 2 MB | W1p 256 KB | W2p 512 KB
    ushort* ph  = (ushort*)d_ws;
    ushort* W1p = (ushort*)((char*)d_ws + (size_t)B_N * U_N * 2);
    ushort* W2p = (ushort*)((char*)d_ws + (size_t)B_N * U_N * 2 + (size_t)D_N * U_N * 2);

    pack_weights<<<192, 256, 0, stream>>>(W1, W2, W1p, W2p);
    proj_h_mfma<<<dim3(B_N / 16, U_N / 128), 256, 0, stream>>>(hidden, W2p, b1, b2, ph);
    attn_kernel<<<B_N / NB, 512, 0, stream>>>(features, W1p, V, bV, ph, out);
}

// Round 8
// 265.524 us; speedup vs baseline: 1.1459x; 1.0598x over previous
//
#include <hip/hip_runtime.h>
#include <math.h>

#define B_N 2048
#define L_N 64
#define D_N 256   // EMBED_DIM
#define U_N 512   // UNITS
#define NB  4     // batches per attn block -> grid 512 = 2 blocks/CU (the R3 regime)

typedef __attribute__((ext_vector_type(8))) short bf16x8;   // 8 bf16 = 4 VGPRs
typedef __attribute__((ext_vector_type(4))) float f32x4;    // MFMA 16x16 acc

// tanh(x) = 1 - 2/(2^(x*2*log2e)+1)
__device__ __forceinline__ float fast_tanh(float x) {
    float e = __builtin_amdgcn_exp2f(x * 2.8853900817779268f);
    float r = __builtin_amdgcn_rcpf(e + 1.0f);
    return fmaf(-2.0f, r, 1.0f);
}
// fp32 -> bf16 round-to-nearest-even
__device__ __forceinline__ ushort f2bf(float x) {
    uint b = __float_as_uint(x);
    uint r = (b + 0x7FFF + ((b >> 16) & 1)) >> 16;
    return (ushort)r;
}
__device__ __forceinline__ float bf2f(ushort u) {
    uint v = ((uint)u) << 16;
    return __uint_as_float(v);
}

// async global->LDS 16B: zero VGPR payload, counted in vmcnt.
// global src is PER-LANE; LDS dest is wave-uniform base (HW adds lane*16).
__device__ __forceinline__ void gll16(const float* g, float* l) {
    __builtin_amdgcn_global_load_lds(
        (const __attribute__((address_space(1))) unsigned int*)g,
        (__attribute__((address_space(3))) unsigned int*)l,
        16, 0, 0);
}

// ---------------------------------------------------------------------------
// K0: pack W1 [256,512] and W2 [512,512] fp32 -> bf16 MFMA B-fragment order.
// chunk g = (ntg*KS + ks)*64 + lane holds W[ks*32 + (lane>>4)*8 + j][ntg*16 + (lane&15)]
// ---------------------------------------------------------------------------
__global__ __launch_bounds__(256) void pack_weights(
    const float* __restrict__ W1, const float* __restrict__ W2,
    ushort* __restrict__ W1p, ushort* __restrict__ W2p)
{
    ushort tmp[8];
    if (blockIdx.x < 64) {
        int g = blockIdx.x * 256 + threadIdx.x;      // 0..16383
        int ntg = g >> 9, ks = (g >> 6) & 7, lane = g & 63;
        int n  = ntg * 16 + (lane & 15);
        int kb = ks * 32 + (lane >> 4) * 8;
#pragma unroll
        for (int j = 0; j < 8; ++j) tmp[j] = f2bf(W1[(kb + j) * U_N + n]);
        *(uint4*)&W1p[(size_t)g * 8] = *(uint4*)tmp;
    } else {
        int g = (blockIdx.x - 64) * 256 + threadIdx.x;  // 0..32767
        int ntg = g >> 10, ks = (g >> 6) & 15, lane = g & 63;
        int n  = ntg * 16 + (lane & 15);
        int kb = ks * 32 + (lane >> 4) * 8;
#pragma unroll
        for (int j = 0; j < 8; ++j) tmp[j] = f2bf(W2[(kb + j) * U_N + n]);
        *(uint4*)&W2p[(size_t)g * 8] = *(uint4*)tmp;
    }
}

// ---------------------------------------------------------------------------
// K1: ph = hidden @ W2 + b1 + b2 via bf16 MFMA, stored bf16. (R0 version)
// ---------------------------------------------------------------------------
__global__ __launch_bounds__(256) void proj_h_mfma(
    const float* __restrict__ hidden, const ushort* __restrict__ W2p,
    const float* __restrict__ b1, const float* __restrict__ b2,
    ushort* __restrict__ ph)
{
    __shared__ ushort As[16 * 512];   // 16 KB

    const int t  = threadIdx.x;
    const int b0 = blockIdx.x * 16;
    const int u0 = blockIdx.y * 128;

#pragma unroll
    for (int i = 0; i < 4; ++i) {
        int f = t + i * 256;
        int m = f >> 6, c = f & 63;
        float4 x0 = *(const float4*)&hidden[(b0 + m) * U_N + c * 8];
        float4 x1 = *(const float4*)&hidden[(b0 + m) * U_N + c * 8 + 4];
        ushort tmp[8] = {f2bf(x0.x), f2bf(x0.y), f2bf(x0.z), f2bf(x0.w),
                         f2bf(x1.x), f2bf(x1.y), f2bf(x1.z), f2bf(x1.w)};
        *(uint4*)&As[(m * 64 + (c ^ (m & 7))) * 8] = *(uint4*)tmp;
    }
    __syncthreads();

    const int w = t >> 6, lane = t & 63;
    const int ml = lane & 15, q = lane >> 4;

    f32x4 acc[2];
#pragma unroll
    for (int nt = 0; nt < 2; ++nt) acc[nt] = (f32x4){0.f, 0.f, 0.f, 0.f};

    for (int ks = 0; ks < 16; ++ks) {
        int c = ks * 4 + q;
        bf16x8 a = *(const bf16x8*)&As[(ml * 64 + (c ^ (ml & 7))) * 8];
        bf16x8 bb[2];
#pragma unroll
        for (int nt = 0; nt < 2; ++nt) {
            int ntg = blockIdx.y * 8 + w * 2 + nt;
            bb[nt] = *(const bf16x8*)&W2p[(size_t)((ntg * 16 + ks) * 64 + lane) * 8];
        }
#pragma unroll
        for (int nt = 0; nt < 2; ++nt)
            acc[nt] = __builtin_amdgcn_mfma_f32_16x16x32_bf16(a, bb[nt], acc[nt], 0, 0, 0);
    }

#pragma unroll
    for (int nt = 0; nt < 2; ++nt) {
        int n = u0 + (w * 2 + nt) * 16 + ml;
        float bias = b1[n] + b2[n];
#pragma unroll
        for (int r = 0; r < 4; ++r)
            ph[(size_t)(b0 + q * 4 + r) * U_N + n] = f2bf(acc[nt][r] + bias);
    }
}

// ---------------------------------------------------------------------------
// K2: fused attention -- R3 regime (256 thr, 4 waves, NB=4, grid 512 =
// 2 blocks/CU: the ONLY regime measured fast; 1-blk/CU variants R4-R7 all
// 137-148 vs R3's 89.5) + in-kernel conversion (kills R3's 65us fbf pass):
//   - S: 32KB fp32 LDS scratch (HALF tile). features DMA'd fp32 via
//     global_load_lds (zero payload VGPRs -> no 128-cliff spill).
//   - single As tile (32KB bf16): legal because compute is split into two
//     m-half passes. Rows 32-63 of batch b convert at the h0->h1 boundary
//     (h0 doesn't read them); rows 0-31 of b+1 convert at tail (after ctx).
//   - each DMA half drains under a half-pass (~2-3k cyc >> HBM lat).
// Regs: acc[2][2]=16 + lp16 + bb8 + av4 + addr ~25 = ~75-90 << 128 cliff.
// LDS 65.3 KB -> 2 blocks/CU. No occupancy hints (R2/R5: ignored).
// ---------------------------------------------------------------------------
__global__ __launch_bounds__(256) void attn_kernel(
    const float* __restrict__ features, const ushort* __restrict__ W1p,
    const float* __restrict__ V, const float* __restrict__ bV,
    const ushort* __restrict__ ph, float* __restrict__ out)
{
    __shared__ ushort As[64 * 256];      // 32 KB bf16, chunk (m,c) at m*32+(c^(m&31))
    __shared__ float  S[32 * 256];       // 32 KB fp32 DMA scratch (one m-half)
    __shared__ float  lpart[4][64];
    __shared__ float  wls[64];

    const int t    = threadIdx.x;        // 0..255
    const int w    = t >> 6;             // 0..3
    const int lane = t & 63;
    const int ml   = lane & 15;
    const int q    = lane >> 4;
    const int b0   = blockIdx.x * NB;

    // wave w DMAs rows (hh*32 + w*8 .. +7) of batch bb_ into its own 8 KB
    // S region (linear fp32; 1 gll16 covers one 256-f32 row: lane*16B).
#define ISSUE_HALF(bb_, hh) do {                                              \
        const float* fsrc_ = features + (size_t)(bb_) * (L_N * D_N)           \
                             + ((hh) * 32 + w * 8) * D_N;                     \
        _Pragma("unroll")                                                     \
        for (int i_ = 0; i_ < 8; ++i_)                                        \
            gll16(fsrc_ + i_ * D_N + lane * 4, &S[w * 2048 + i_ * 256]);      \
    } while (0)

    // wave w converts its own 8 rows: lane reads float4 (16B), writes uint2
    // (8B) at the swizzled chunk: elem e=lane*4 -> chunk c=lane>>1, half lane&1.
#define CONV_HALF(hh) do {                                                    \
        _Pragma("unroll")                                                     \
        for (int i_ = 0; i_ < 8; ++i_) {                                      \
            float4 x_ = *(const float4*)&S[w * 2048 + i_ * 256 + lane * 4];   \
            ushort tv_[4] = {f2bf(x_.x), f2bf(x_.y), f2bf(x_.z), f2bf(x_.w)}; \
            int m_ = (hh) * 32 + w * 8 + i_, c_ = lane >> 1;                  \
            *(uint2*)&As[(m_ * 32 + (c_ ^ (m_ & 31))) * 8 + (lane & 1) * 4]   \
                = *(uint2*)tv_;                                               \
        }                                                                     \
    } while (0)

    // half-pass hh: wave computes rows hh*32..+31 x its 128-u strip,
    // folding tanh(.+ph)*V into lp[hh*8 + mt*4 + r].
#define HALFPASS(hh, b_) do {                                                 \
        for (int uc = 0; uc < 4; ++uc) {                                      \
            f32x4 acc[2][2];                                                  \
            _Pragma("unroll")                                                 \
            for (int mt = 0; mt < 2; ++mt)                                    \
                _Pragma("unroll")                                             \
                for (int nt = 0; nt < 2; ++nt)                                \
                    acc[mt][nt] = (f32x4){0.f, 0.f, 0.f, 0.f};                \
            for (int ks = 0; ks < 8; ++ks) {                                  \
                bf16x8 bb[2];                                                 \
                _Pragma("unroll")                                             \
                for (int nt = 0; nt < 2; ++nt)                                \
                    bb[nt] = *(const bf16x8*)&W1w[(size_t)(((uc * 2 + nt) * 8 + ks) * 64 + lane) * 8]; \
                _Pragma("unroll")                                             \
                for (int mt = 0; mt < 2; ++mt) {                              \
                    int m_ = (hh) * 32 + mt * 16 + ml, c_ = ks * 4 + q;       \
                    bf16x8 av = *(const bf16x8*)&As[(m_ * 32 + (c_ ^ (m_ & 31))) * 8]; \
                    _Pragma("unroll")                                         \
                    for (int nt = 0; nt < 2; ++nt)                            \
                        acc[mt][nt] = __builtin_amdgcn_mfma_f32_16x16x32_bf16( \
                            av, bb[nt], acc[mt][nt], 0, 0, 0);                \
                }                                                             \
            }                                                                 \
            _Pragma("unroll")                                                 \
            for (int nt = 0; nt < 2; ++nt) {                                  \
                int n_ = w * 128 + uc * 32 + nt * 16 + ml;                    \
                float phv_ = bf2f(ph[(size_t)(b_) * U_N + n_]);               \
                float vv_  = V[n_];                                           \
                _Pragma("unroll")                                             \
                for (int mt = 0; mt < 2; ++mt)                                \
                    _Pragma("unroll")                                         \
                    for (int r = 0; r < 4; ++r) {                             \
                        float s_ = fast_tanh(acc[mt][nt][r] + phv_);          \
                        lp[(hh) * 8 + mt * 4 + r] = fmaf(s_, vv_, lp[(hh) * 8 + mt * 4 + r]); \
                    }                                                         \
            }                                                                 \
        }                                                                     \
    } while (0)

    const ushort* W1w = W1p + (size_t)(w * 8) * 8 * 64 * 8;  // wave's 128-u strip

    // prologue: rows 0-31 of b0 (DMA+convert), then pre-issue rows 32-63
    ISSUE_HALF(b0, 0);
    asm volatile("s_waitcnt vmcnt(0)" ::: "memory");
    CONV_HALF(0);
    ISSUE_HALF(b0, 1);
    __syncthreads();

    for (int bi = 0; bi < NB; ++bi) {
        const int b = b0 + bi;
        const bool pre = (bi + 1 < NB);

        float lp[16];
#pragma unroll
        for (int j = 0; j < 16; ++j) lp[j] = 0.f;

        // h=0 pass (reads As rows 0-31 = batch b)
        HALFPASS(0, b);

        // h-boundary: drain own DMA (rows 32-63 of b), convert, issue
        // rows 0-31 of b+1 (S region now free; drains under h=1 + epilogue)
        asm volatile("s_waitcnt vmcnt(0)" ::: "memory");
        CONV_HALF(1);
        if (pre) ISSUE_HALF(b + 1, 0);
        __syncthreads();

        // h=1 pass (reads As rows 32-63 = batch b)
        HALFPASS(1, b);

        // reduce over the 16 n-lanes (xor 1,2,4,8 stays within q-group)
#pragma unroll
        for (int off = 1; off <= 8; off <<= 1)
#pragma unroll
            for (int j = 0; j < 16; ++j)
                lp[j] += __shfl_xor(lp[j], off);

        if (ml == 0) {
#pragma unroll
            for (int hh = 0; hh < 2; ++hh)
#pragma unroll
                for (int mt = 0; mt < 2; ++mt)
#pragma unroll
                    for (int r = 0; r < 4; ++r)
                        lpart[w][hh * 32 + mt * 16 + q * 4 + r] = lp[hh * 8 + mt * 4 + r];
        }
        __syncthreads();   // BARRIER B: lpart ready

        if (t < 64) {
            float lsum = bV[0] + lpart[0][t] + lpart[1][t] + lpart[2][t] + lpart[3][t];
            float mx = lsum;
#pragma unroll
            for (int off = 32; off > 0; off >>= 1)
                mx = fmaxf(mx, __shfl_xor(mx, off));
            float e = __expf(lsum - mx);
            float ssum = e;
#pragma unroll
            for (int off = 32; off > 0; off >>= 1)
                ssum += __shfl_xor(ssum, off);
            float wt = e / ssum;
            wls[t] = wt;
            out[(size_t)B_N * D_N + (size_t)b * L_N + t] = wt;
        }
        __syncthreads();   // BARRIER C: wls ready

        // context[d] = sum_l w_l * f[l][d], from LDS bf16 (t == d)
        float ctx = 0.f;
#pragma unroll 16
        for (int l = 0; l < L_N; ++l) {
            ushort u = As[(l * 32 + ((t >> 3) ^ (l & 31))) * 8 + (t & 7)];
            ctx = fmaf(wls[l], bf2f(u), ctx);
        }
        out[(size_t)b * D_N + t] = ctx;
        __syncthreads();   // BARRIER D: all ctx reads of As done

        // tail: drain own DMA (rows 0-31 of b+1), convert into As rows 0-31,
        // issue rows 32-63 of b+1 (drains under next iter's h=0)
        if (pre) {
            asm volatile("s_waitcnt vmcnt(0)" ::: "memory");
            CONV_HALF(0);
            ISSUE_HALF(b + 1, 1);
        }
        __syncthreads();   // BARRIER E: As rows 0-31 visible for next h=0
    }
#undef ISSUE_HALF
#undef CONV_HALF
#undef HALFPASS
}

// ---------------------------------------------------------------------------
extern "C" void kernel_launch(void* const* d_in, const int* in_sizes, int n_in,
                              void* d_out, int out_size, void* d_ws, size_t ws_size,
                              hipStream_t stream) {
    const float* features = (const float*)d_in[0];
    const float* hidden   = (const float*)d_in[1];
    const float* W1       = (const float*)d_in[2];
    const float* b1       = (const float*)d_in[3];
    const float* W2       = (const float*)d_in[4];
    const float* b2       = (const float*)d_in[5];
    const float* V        = (const float*)d_in[6];
    const float* bV       = (const float*)d_in[7];
    float* out = (float*)d_out;

    // ws: ph bf16 2 MB | W1p 256 KB | W2p 512 KB
    ushort* ph  = (ushort*)d_ws;
    ushort* W1p = (ushort*)((char*)d_ws + (size_t)B_N * U_N * 2);
    ushort* W2p = (ushort*)((char*)d_ws + (size_t)B_N * U_N * 2 + (size_t)D_N * U_N * 2);

    pack_weights<<<192, 256, 0, stream>>>(W1, W2, W1p, W2p);
    proj_h_mfma<<<dim3(B_N / 16, U_N / 128), 256, 0, stream>>>(hidden, W2p, b1, b2, ph);
    attn_kernel<<<B_N / NB, 256, 0, stream>>>(features, W1p, V, bV, ph, out);
}